// Round 9
// baseline (2258.231 us; speedup 1.0000x reference)
//
#include <hip/hip_runtime.h>
#include <hip/hip_fp16.h>
#include <stdint.h>

// Problem constants
#define TT   1024
#define NIN  64
#define HH   128
#define RPB  16          // batch rows per WG = MFMA N
#define NWG  32          // 512 / 16
#define NTHR 512         // 8 waves, 2 waves/SIMD -> 256-reg unified budget

// A-fragment index bases (1 frag = 1KB = 64 lanes x 16B)
#define FB_IH0 0         // 24 mt * 2 kt = 48 frags
#define FB_HH0 48        // 24 * 4 = 96
#define FB_IH1 144       // 96
#define FB_HH1 240       // 96   -> 336 frags = 344064 B in d_ws

typedef _Float16 f16x8 __attribute__((ext_vector_type(8)));
typedef float    f32x4 __attribute__((ext_vector_type(4)));
typedef _Float16 half2v __attribute__((ext_vector_type(2)));

__device__ __forceinline__ uint32_t pack2f(float a, float b) {
    half2v v; v[0] = (_Float16)a; v[1] = (_Float16)b;
    return __builtin_bit_cast(uint32_t, v);
}
__device__ __forceinline__ f16x8 bc8(uint4 u) { return __builtin_bit_cast(f16x8, u); }
__device__ __forceinline__ float sigm(float v)     { return 1.f / (1.f + __expf(-v)); }
__device__ __forceinline__ float tanhfast(float v) { return 2.f / (1.f + __expf(-2.f * v)) - 1.f; }

// D = A(16x32) * B(32x16) + C, f16 in / f32 acc. A,B,C register-resident.
#define MF(c_, a_, b_) c_ = __builtin_amdgcn_mfma_f32_16x16x32_f16(bc8(a_), bc8(b_), c_, 0, 0, 0);

#define UNPK2(a_, b_, s_) { half2v t_ = __builtin_bit_cast(half2v, s_); a_ = (float)t_[0]; b_ = (float)t_[1]; }

// GRU combine for one (j,row) unit held in lane position ri of the C frags.
#define CMB(ri_, CR_, CZ_, CX_, CH_, BR_, BZ_, BXX_, BHH_, HO_, NH_) { \
    float rg_ = sigm(CR_[ri_] + BR_);                                   \
    float zg_ = sigm(CZ_[ri_] + BZ_);                                   \
    float ng_ = tanhfast(CX_[ri_] + BXX_ + rg_ * (CH_[ri_] + BHH_));    \
    NH_ = ng_ + zg_ * (HO_ - ng_); HO_ = NH_; }

// ---------------- pre-kernel: f32 weights -> f16 MFMA A-fragments ----------------
// Frag (matrix, mt, kt), lane l holds W[mt*16 + (l&15)][kt*32 + (l>>4)*8 + j], j=0..7.
__global__ __launch_bounds__(256) void pack_frags(
    const float* __restrict__ Wih0, const float* __restrict__ Whh0,
    const float* __restrict__ Wih1, const float* __restrict__ Whh1,
    uint4* __restrict__ ws)
{
    const int tid = blockIdx.x * 256 + threadIdx.x;   // 0..21503 (84 blocks)
    const int f = tid >> 6, l = tid & 63;
    const float* W; int K, mt, kt;
    if (f < 48)       { W = Wih0; K = NIN; mt = f >> 1;        kt = f & 1; }
    else if (f < 144) { W = Whh0; K = HH;  mt = (f - 48) >> 2;  kt = (f - 48) & 3; }
    else if (f < 240) { W = Wih1; K = HH;  mt = (f - 144) >> 2; kt = (f - 144) & 3; }
    else              { W = Whh1; K = HH;  mt = (f - 240) >> 2; kt = (f - 240) & 3; }
    const float* s = W + (mt * 16 + (l & 15)) * K + kt * 32 + (l >> 4) * 8;
    uint4 o;
    o.x = pack2f(s[0], s[1]); o.y = pack2f(s[2], s[3]);
    o.z = pack2f(s[4], s[5]); o.w = pack2f(s[6], s[7]);
    ws[tid] = o;
}

// ---------------- main kernel ----------------
// Wave w owns m-tiles {w, w+8, 16+w} of each matrix -> its lanes hold the
// (r,z,n) pre-acts for hidden j in [16w,16w+16), all 16 rows: combine is in-wave.
// D/C layout: col(=batch row)=lane&15, gate_local=(lane>>4)*4+ri  [m89].
__global__ __launch_bounds__(NTHR)
__attribute__((amdgpu_waves_per_eu(2, 2)))
void gru_mfma(
    const float* __restrict__ x, const uint4* __restrict__ wsA,
    const float* __restrict__ bih0, const float* __restrict__ bhh0,
    const float* __restrict__ bih1, const float* __restrict__ bhh1,
    const float* __restrict__ fc1w, const float* __restrict__ fc1b,
    const float* __restrict__ fc2w, const float* __restrict__ fc2b,
    float* __restrict__ out)
{
    // B-fragment buffers (f16, MFMA B layout), parity double-buffered.
    // byte(kt, lane, j) holds state[row = lane&15][k = kt*32 + (lane>>4)*8 + j]
    __shared__ uint4 xF[2][2][64];    // x_t      (K=64)
    __shared__ uint4 h0F[2][4][64];   // h0 state (K=128)
    __shared__ uint4 h1F[2][4][64];   // h1 state
    __shared__ float h1f[RPB][HH];    // final h1 (FC head)
    __shared__ float pFC[RPB][HH];
    __shared__ float p2[RPB][8];

    const int lid = threadIdx.x, w = lid >> 6, l = lid & 63;
    const int row0 = blockIdx.x * RPB;

    // ---- A-fragments: 42 named uint4 (168 regs; MFMA reads AGPRs natively) ----
#define DECLF(nm, idx) uint4 nm = wsA[(idx) * 64 + l];
    DECLF(a0r_i0, FB_IH0 + (w)*2 + 0)     DECLF(a0r_i1, FB_IH0 + (w)*2 + 1)
    DECLF(a0r_h0, FB_HH0 + (w)*4 + 0)     DECLF(a0r_h1, FB_HH0 + (w)*4 + 1)
    DECLF(a0r_h2, FB_HH0 + (w)*4 + 2)     DECLF(a0r_h3, FB_HH0 + (w)*4 + 3)
    DECLF(a0z_i0, FB_IH0 + (w+8)*2 + 0)   DECLF(a0z_i1, FB_IH0 + (w+8)*2 + 1)
    DECLF(a0z_h0, FB_HH0 + (w+8)*4 + 0)   DECLF(a0z_h1, FB_HH0 + (w+8)*4 + 1)
    DECLF(a0z_h2, FB_HH0 + (w+8)*4 + 2)   DECLF(a0z_h3, FB_HH0 + (w+8)*4 + 3)
    DECLF(a0n_i0, FB_IH0 + (16+w)*2 + 0)  DECLF(a0n_i1, FB_IH0 + (16+w)*2 + 1)
    DECLF(a0n_h0, FB_HH0 + (16+w)*4 + 0)  DECLF(a0n_h1, FB_HH0 + (16+w)*4 + 1)
    DECLF(a0n_h2, FB_HH0 + (16+w)*4 + 2)  DECLF(a0n_h3, FB_HH0 + (16+w)*4 + 3)
    DECLF(a1r_i0, FB_IH1 + (w)*4 + 0)     DECLF(a1r_i1, FB_IH1 + (w)*4 + 1)
    DECLF(a1r_i2, FB_IH1 + (w)*4 + 2)     DECLF(a1r_i3, FB_IH1 + (w)*4 + 3)
    DECLF(a1r_h0, FB_HH1 + (w)*4 + 0)     DECLF(a1r_h1, FB_HH1 + (w)*4 + 1)
    DECLF(a1r_h2, FB_HH1 + (w)*4 + 2)     DECLF(a1r_h3, FB_HH1 + (w)*4 + 3)
    DECLF(a1z_i0, FB_IH1 + (w+8)*4 + 0)   DECLF(a1z_i1, FB_IH1 + (w+8)*4 + 1)
    DECLF(a1z_i2, FB_IH1 + (w+8)*4 + 2)   DECLF(a1z_i3, FB_IH1 + (w+8)*4 + 3)
    DECLF(a1z_h0, FB_HH1 + (w+8)*4 + 0)   DECLF(a1z_h1, FB_HH1 + (w+8)*4 + 1)
    DECLF(a1z_h2, FB_HH1 + (w+8)*4 + 2)   DECLF(a1z_h3, FB_HH1 + (w+8)*4 + 3)
    DECLF(a1n_i0, FB_IH1 + (16+w)*4 + 0)  DECLF(a1n_i1, FB_IH1 + (16+w)*4 + 1)
    DECLF(a1n_i2, FB_IH1 + (16+w)*4 + 2)  DECLF(a1n_i3, FB_IH1 + (16+w)*4 + 3)
    DECLF(a1n_h0, FB_HH1 + (16+w)*4 + 0)  DECLF(a1n_h1, FB_HH1 + (16+w)*4 + 1)
    DECLF(a1n_h2, FB_HH1 + (16+w)*4 + 2)  DECLF(a1n_h3, FB_HH1 + (16+w)*4 + 3)

    // ---- biases, f16x2-packed (16 regs). j0 = first hidden unit of this lane. ----
    const int j0 = 16 * w + 4 * (l >> 4);
    uint32_t B0r01 = pack2f(bih0[j0]+bhh0[j0],       bih0[j0+1]+bhh0[j0+1]);
    uint32_t B0r23 = pack2f(bih0[j0+2]+bhh0[j0+2],   bih0[j0+3]+bhh0[j0+3]);
    uint32_t B0z01 = pack2f(bih0[128+j0]+bhh0[128+j0],     bih0[129+j0]+bhh0[129+j0]);
    uint32_t B0z23 = pack2f(bih0[130+j0]+bhh0[130+j0],     bih0[131+j0]+bhh0[131+j0]);
    uint32_t B0x01 = pack2f(bih0[256+j0], bih0[257+j0]);
    uint32_t B0x23 = pack2f(bih0[258+j0], bih0[259+j0]);
    uint32_t B0h01 = pack2f(bhh0[256+j0], bhh0[257+j0]);
    uint32_t B0h23 = pack2f(bhh0[258+j0], bhh0[259+j0]);
    uint32_t B1r01 = pack2f(bih1[j0]+bhh1[j0],       bih1[j0+1]+bhh1[j0+1]);
    uint32_t B1r23 = pack2f(bih1[j0+2]+bhh1[j0+2],   bih1[j0+3]+bhh1[j0+3]);
    uint32_t B1z01 = pack2f(bih1[128+j0]+bhh1[128+j0],     bih1[129+j0]+bhh1[129+j0]);
    uint32_t B1z23 = pack2f(bih1[130+j0]+bhh1[130+j0],     bih1[131+j0]+bhh1[131+j0]);
    uint32_t B1x01 = pack2f(bih1[256+j0], bih1[257+j0]);
    uint32_t B1x23 = pack2f(bih1[258+j0], bih1[259+j0]);
    uint32_t B1h01 = pack2f(bhh1[256+j0], bhh1[257+j0]);
    uint32_t B1h23 = pack2f(bhh1[258+j0], bhh1[259+j0]);

    float h0o0 = 0.f, h0o1 = 0.f, h0o2 = 0.f, h0o3 = 0.f;   // h_old in regs
    float h1o0 = 0.f, h1o1 = 0.f, h1o2 = 0.f, h1o3 = 0.f;

    // zero h-frag buffers (both parities): 512+512 uint4, one of each per thread
    { uint4 z4 = {0u,0u,0u,0u};
      (&h0F[0][0][0])[lid] = z4;
      (&h1F[0][0][0])[lid] = z4; }

    // x stager: this thread owns (row = lid>>5, k2 = (lid&31)*2) of every x_t
    const int xrow = lid >> 5, xk = (lid & 31) * 2;
    const float* xbase = x + (size_t)(row0 + xrow) * TT * NIN + xk;
    const int xoff = ((xk >> 5) << 10) + (((((xk & 31) >> 3) * 16) + xrow) << 4) + ((xk & 7) << 1);
    float2 xr2;
    { float2 v0 = *(const float2*)xbase;                     // x_0
      *(uint32_t*)((char*)&xF[0][0][0] + xoff) = pack2f(v0.x, v0.y);
      xr2 = *(const float2*)(xbase + NIN); }                 // x_1

    // h-frag write offset for this lane (J = j0+ri, row = l&15)
    const int hoff = ((w >> 1) << 10)
                   + ((((2 * (w & 1) + ((l >> 4) >> 1)) * 16) + (l & 15)) << 4)
                   + (((l >> 4) & 1) << 3);

    __syncthreads();

    // Iter i: layer0 computes h0[i] (i<TT); layer1 computes h1[i-1] (i>=1).
    for (int i = 0; i <= TT; ++i) {
        const int p = i & 1;
        const uint4* bb0 = &h0F[p][0][0];                    // h0[i-1] frags
        uint4 bh00 = bb0[l], bh01 = bb0[64+l], bh02 = bb0[128+l], bh03 = bb0[192+l];

        if (i < TT) {                                        // ---- layer 0 ----
            const uint4* bxv = &xF[p][0][0];
            uint4 bx0 = bxv[l], bx1 = bxv[64 + l];
            f32x4 cr = {0,0,0,0}, cz = {0,0,0,0}, cx = {0,0,0,0}, ch = {0,0,0,0};
            MF(cr, a0r_i0, bx0)  MF(cr, a0r_i1, bx1)
            MF(cr, a0r_h0, bh00) MF(cr, a0r_h1, bh01) MF(cr, a0r_h2, bh02) MF(cr, a0r_h3, bh03)
            MF(cz, a0z_i0, bx0)  MF(cz, a0z_i1, bx1)
            MF(cz, a0z_h0, bh00) MF(cz, a0z_h1, bh01) MF(cz, a0z_h2, bh02) MF(cz, a0z_h3, bh03)
            MF(cx, a0n_i0, bx0)  MF(cx, a0n_i1, bx1)
            MF(ch, a0n_h0, bh00) MF(ch, a0n_h1, bh01) MF(ch, a0n_h2, bh02) MF(ch, a0n_h3, bh03)
            float vr0,vr1,vr2,vr3, vz0,vz1,vz2,vz3, vx0,vx1,vx2,vx3, vh0,vh1,vh2,vh3;
            UNPK2(vr0,vr1,B0r01) UNPK2(vr2,vr3,B0r23)
            UNPK2(vz0,vz1,B0z01) UNPK2(vz2,vz3,B0z23)
            UNPK2(vx0,vx1,B0x01) UNPK2(vx2,vx3,B0x23)
            UNPK2(vh0,vh1,B0h01) UNPK2(vh2,vh3,B0h23)
            float nh0, nh1, nh2, nh3;
            CMB(0, cr,cz,cx,ch, vr0,vz0,vx0,vh0, h0o0, nh0)
            CMB(1, cr,cz,cx,ch, vr1,vz1,vx1,vh1, h0o1, nh1)
            CMB(2, cr,cz,cx,ch, vr2,vz2,vx2,vh2, h0o2, nh2)
            CMB(3, cr,cz,cx,ch, vr3,vz3,vx3,vh3, h0o3, nh3)
            uint2 hw; hw.x = pack2f(nh0, nh1); hw.y = pack2f(nh2, nh3);
            *(uint2*)((char*)&h0F[1 - p][0][0] + hoff) = hw;
        }

        if (i >= 1) {                                        // ---- layer 1 ----
            const uint4* bb1 = &h1F[p][0][0];                // h1[i-2] frags
            uint4 bh10 = bb1[l], bh11 = bb1[64+l], bh12 = bb1[128+l], bh13 = bb1[192+l];
            f32x4 cr = {0,0,0,0}, cz = {0,0,0,0}, cx = {0,0,0,0}, ch = {0,0,0,0};
            MF(cr, a1r_i0, bh00) MF(cr, a1r_i1, bh01) MF(cr, a1r_i2, bh02) MF(cr, a1r_i3, bh03)
            MF(cr, a1r_h0, bh10) MF(cr, a1r_h1, bh11) MF(cr, a1r_h2, bh12) MF(cr, a1r_h3, bh13)
            MF(cz, a1z_i0, bh00) MF(cz, a1z_i1, bh01) MF(cz, a1z_i2, bh02) MF(cz, a1z_i3, bh03)
            MF(cz, a1z_h0, bh10) MF(cz, a1z_h1, bh11) MF(cz, a1z_h2, bh12) MF(cz, a1z_h3, bh13)
            MF(cx, a1n_i0, bh00) MF(cx, a1n_i1, bh01) MF(cx, a1n_i2, bh02) MF(cx, a1n_i3, bh03)
            MF(ch, a1n_h0, bh10) MF(ch, a1n_h1, bh11) MF(ch, a1n_h2, bh12) MF(ch, a1n_h3, bh13)
            float vr0,vr1,vr2,vr3, vz0,vz1,vz2,vz3, vx0,vx1,vx2,vx3, vh0,vh1,vh2,vh3;
            UNPK2(vr0,vr1,B1r01) UNPK2(vr2,vr3,B1r23)
            UNPK2(vz0,vz1,B1z01) UNPK2(vz2,vz3,B1z23)
            UNPK2(vx0,vx1,B1x01) UNPK2(vx2,vx3,B1x23)
            UNPK2(vh0,vh1,B1h01) UNPK2(vh2,vh3,B1h23)
            float nh0, nh1, nh2, nh3;
            CMB(0, cr,cz,cx,ch, vr0,vz0,vx0,vh0, h1o0, nh0)
            CMB(1, cr,cz,cx,ch, vr1,vz1,vx1,vh1, h1o1, nh1)
            CMB(2, cr,cz,cx,ch, vr2,vz2,vx2,vh2, h1o2, nh2)
            CMB(3, cr,cz,cx,ch, vr3,vz3,vx3,vh3, h1o3, nh3)
            uint2 hw; hw.x = pack2f(nh0, nh1); hw.y = pack2f(nh2, nh3);
            *(uint2*)((char*)&h1F[1 - p][0][0] + hoff) = hw;
        }

        // x staging into the buffer next iter reads
        if (i + 1 < TT)
            *(uint32_t*)((char*)&xF[1 - p][0][0] + xoff) = pack2f(xr2.x, xr2.y);
        if (i + 2 < TT)
            xr2 = *(const float2*)(xbase + (size_t)(i + 2) * NIN);

        __syncthreads();
    }

    // ---------------- FC head ----------------
    { f32x4 hv; hv[0] = h1o0; hv[1] = h1o1; hv[2] = h1o2; hv[3] = h1o3;
      *(f32x4*)&h1f[l & 15][16 * w + 4 * (l >> 4)] = hv; }
    __syncthreads();

    { const int fcj = lid & 127, rb = lid >> 7;              // 4 rows per thread
      float a0 = fc1b[fcj], a1 = a0, a2 = a0, a3 = a0;
      const float* fw = fc1w + fcj * HH;
      #pragma unroll 4
      for (int k = 0; k < HH; ++k) {
          float wv = fw[k];
          a0 = fmaf(wv, h1f[rb][k], a0);
          a1 = fmaf(wv, h1f[rb + 4][k], a1);
          a2 = fmaf(wv, h1f[rb + 8][k], a2);
          a3 = fmaf(wv, h1f[rb + 12][k], a3);
      }
      float s2 = fc2w[fcj];
      pFC[rb][fcj]      = fmaxf(a0, 0.f) * s2;
      pFC[rb + 4][fcj]  = fmaxf(a1, 0.f) * s2;
      pFC[rb + 8][fcj]  = fmaxf(a2, 0.f) * s2;
      pFC[rb + 12][fcj] = fmaxf(a3, 0.f) * s2; }
    __syncthreads();
    if (lid < 128) {
        const int r = lid >> 3, seg = lid & 7;
        float s = 0.f;
        #pragma unroll
        for (int m2 = 0; m2 < 16; ++m2) s += pFC[r][seg * 16 + m2];
        p2[r][seg] = s;
    }
    __syncthreads();
    if (lid < RPB) {
        float s = fc2b[0];
        #pragma unroll
        for (int q = 0; q < 8; ++q) s += p2[lid][q];
        out[row0 + lid] = s;
    }
}

extern "C" void kernel_launch(void* const* d_in, const int* in_sizes, int n_in,
                              void* d_out, int out_size, void* d_ws, size_t ws_size,
                              hipStream_t stream) {
    const float* x    = (const float*)d_in[0];
    const float* Wih0 = (const float*)d_in[1];
    const float* Whh0 = (const float*)d_in[2];
    const float* bih0 = (const float*)d_in[3];
    const float* bhh0 = (const float*)d_in[4];
    const float* Wih1 = (const float*)d_in[5];
    const float* Whh1 = (const float*)d_in[6];
    const float* bih1 = (const float*)d_in[7];
    const float* bhh1 = (const float*)d_in[8];
    const float* fc1w = (const float*)d_in[9];
    const float* fc1b = (const float*)d_in[10];
    const float* fc2w = (const float*)d_in[11];
    const float* fc2b = (const float*)d_in[12];

    uint4* ws = (uint4*)d_ws;   // 336 KB of f16 A-fragments

    pack_frags<<<dim3(84), dim3(256), 0, stream>>>(Wih0, Whh0, Wih1, Whh1, ws);
    gru_mfma<<<dim3(NWG), dim3(NTHR), 0, stream>>>(
        x, ws, bih0, bhh0, bih1, bhh1, fc1w, fc1b, fc2w, fc2b, (float*)d_out);
}

// Round 10
// 2228.463 us; speedup vs baseline: 1.0134x; 1.0134x over previous
//
#include <hip/hip_runtime.h>
#include <hip/hip_fp16.h>
#include <stdint.h>

// Problem constants
#define TT   1024
#define NIN  64
#define HH   128
#define RPB  16          // batch rows per WG = MFMA N
#define NWG  32          // 512 / 16
#define NTHR 512         // 8 waves, 2 waves/SIMD -> 256-reg unified budget

// A-fragment index bases (1 frag = 1KB = 64 lanes x 16B)
#define FB_IH0 0         // 24 mt * 2 kt = 48 frags
#define FB_HH0 48        // 24 * 4 = 96
#define FB_IH1 144       // 96
#define FB_HH1 240       // 96   -> 336 frags = 344064 B in d_ws

typedef _Float16 f16x8 __attribute__((ext_vector_type(8)));
typedef float    f32x4 __attribute__((ext_vector_type(4)));
typedef _Float16 half2v __attribute__((ext_vector_type(2)));

__device__ __forceinline__ uint32_t pack2f(float a, float b) {
    half2v v; v[0] = (_Float16)a; v[1] = (_Float16)b;
    return __builtin_bit_cast(uint32_t, v);
}
__device__ __forceinline__ f16x8 bc8(uint4 u) { return __builtin_bit_cast(f16x8, u); }
__device__ __forceinline__ float sigm(float v)     { return 1.f / (1.f + __expf(-v)); }
__device__ __forceinline__ float tanhfast(float v) { return 2.f / (1.f + __expf(-2.f * v)) - 1.f; }

// D = A(16x32) * B(32x16) + C, f16 in / f32 acc. A,B,C register-resident.
#define MF(c_, a_, b_) c_ = __builtin_amdgcn_mfma_f32_16x16x32_f16(bc8(a_), bc8(b_), c_, 0, 0, 0);

#define UNPK2(a_, b_, s_) { half2v t_ = __builtin_bit_cast(half2v, s_); a_ = (float)t_[0]; b_ = (float)t_[1]; }

// GRU combine for one (j,row) unit held in lane position ri of the C frags.
#define CMB(ri_, CR_, CZ_, CX_, CH_, BR_, BZ_, BXX_, BHH_, HO_, NH_) { \
    float rg_ = sigm(CR_[ri_] + BR_);                                   \
    float zg_ = sigm(CZ_[ri_] + BZ_);                                   \
    float ng_ = tanhfast(CX_[ri_] + BXX_ + rg_ * (CH_[ri_] + BHH_));    \
    NH_ = ng_ + zg_ * (HO_ - ng_); HO_ = NH_; }

// Counted-vmcnt barrier (T4): drain LDS only; leave global prefetch loads in
// flight across the barrier. (__syncthreads would emit s_waitcnt vmcnt(0) and
// serialize the x prefetch's HBM latency into every step.)
#define BARS() { asm volatile("s_waitcnt lgkmcnt(0)" ::: "memory");  \
                 __builtin_amdgcn_s_barrier();                        \
                 __builtin_amdgcn_sched_barrier(0);                   \
                 asm volatile("" ::: "memory"); }

// ---------------- pre-kernel: f32 weights -> f16 MFMA A-fragments ----------------
// Frag (matrix, mt, kt), lane l holds W[mt*16 + (l&15)][kt*32 + (l>>4)*8 + j], j=0..7.
__global__ __launch_bounds__(256) void pack_frags(
    const float* __restrict__ Wih0, const float* __restrict__ Whh0,
    const float* __restrict__ Wih1, const float* __restrict__ Whh1,
    uint4* __restrict__ ws)
{
    const int tid = blockIdx.x * 256 + threadIdx.x;   // 0..21503 (84 blocks)
    const int f = tid >> 6, l = tid & 63;
    const float* W; int K, mt, kt;
    if (f < 48)       { W = Wih0; K = NIN; mt = f >> 1;        kt = f & 1; }
    else if (f < 144) { W = Whh0; K = HH;  mt = (f - 48) >> 2;  kt = (f - 48) & 3; }
    else if (f < 240) { W = Wih1; K = HH;  mt = (f - 144) >> 2; kt = (f - 144) & 3; }
    else              { W = Whh1; K = HH;  mt = (f - 240) >> 2; kt = (f - 240) & 3; }
    const float* s = W + (mt * 16 + (l & 15)) * K + kt * 32 + (l >> 4) * 8;
    uint4 o;
    o.x = pack2f(s[0], s[1]); o.y = pack2f(s[2], s[3]);
    o.z = pack2f(s[4], s[5]); o.w = pack2f(s[6], s[7]);
    ws[tid] = o;
}

// ---------------- main kernel ----------------
// Wave w owns m-tiles {w, w+8, 16+w} of each matrix -> its lanes hold the
// (r,z,n) pre-acts for hidden j in [16w,16w+16), all 16 rows: combine is in-wave.
// D/C layout: col(=batch row)=lane&15, gate_local=(lane>>4)*4+ri  [m89].
__global__ __launch_bounds__(NTHR)
__attribute__((amdgpu_waves_per_eu(2, 2)))
void gru_mfma(
    const float* __restrict__ x, const uint4* __restrict__ wsA,
    const float* __restrict__ bih0, const float* __restrict__ bhh0,
    const float* __restrict__ bih1, const float* __restrict__ bhh1,
    const float* __restrict__ fc1w, const float* __restrict__ fc1b,
    const float* __restrict__ fc2w, const float* __restrict__ fc2b,
    float* __restrict__ out)
{
    // B-fragment buffers (f16, MFMA B layout), parity double-buffered.
    // byte(kt, lane, j) holds state[row = lane&15][k = kt*32 + (lane>>4)*8 + j]
    __shared__ uint4 xF[2][2][64];    // x_t      (K=64)
    __shared__ uint4 h0F[2][4][64];   // h0 state (K=128)
    __shared__ uint4 h1F[2][4][64];   // h1 state
    __shared__ float h1f[RPB][HH];    // final h1 (FC head)
    __shared__ float pFC[RPB][HH];
    __shared__ float p2[RPB][8];

    const int lid = threadIdx.x, w = lid >> 6, l = lid & 63;
    const int row0 = blockIdx.x * RPB;

    // ---- A-fragments: 42 named uint4 (168 regs; MFMA reads AGPRs natively) ----
#define DECLF(nm, idx) uint4 nm = wsA[(idx) * 64 + l];
    DECLF(a0r_i0, FB_IH0 + (w)*2 + 0)     DECLF(a0r_i1, FB_IH0 + (w)*2 + 1)
    DECLF(a0r_h0, FB_HH0 + (w)*4 + 0)     DECLF(a0r_h1, FB_HH0 + (w)*4 + 1)
    DECLF(a0r_h2, FB_HH0 + (w)*4 + 2)     DECLF(a0r_h3, FB_HH0 + (w)*4 + 3)
    DECLF(a0z_i0, FB_IH0 + (w+8)*2 + 0)   DECLF(a0z_i1, FB_IH0 + (w+8)*2 + 1)
    DECLF(a0z_h0, FB_HH0 + (w+8)*4 + 0)   DECLF(a0z_h1, FB_HH0 + (w+8)*4 + 1)
    DECLF(a0z_h2, FB_HH0 + (w+8)*4 + 2)   DECLF(a0z_h3, FB_HH0 + (w+8)*4 + 3)
    DECLF(a0n_i0, FB_IH0 + (16+w)*2 + 0)  DECLF(a0n_i1, FB_IH0 + (16+w)*2 + 1)
    DECLF(a0n_h0, FB_HH0 + (16+w)*4 + 0)  DECLF(a0n_h1, FB_HH0 + (16+w)*4 + 1)
    DECLF(a0n_h2, FB_HH0 + (16+w)*4 + 2)  DECLF(a0n_h3, FB_HH0 + (16+w)*4 + 3)
    DECLF(a1r_i0, FB_IH1 + (w)*4 + 0)     DECLF(a1r_i1, FB_IH1 + (w)*4 + 1)
    DECLF(a1r_i2, FB_IH1 + (w)*4 + 2)     DECLF(a1r_i3, FB_IH1 + (w)*4 + 3)
    DECLF(a1r_h0, FB_HH1 + (w)*4 + 0)     DECLF(a1r_h1, FB_HH1 + (w)*4 + 1)
    DECLF(a1r_h2, FB_HH1 + (w)*4 + 2)     DECLF(a1r_h3, FB_HH1 + (w)*4 + 3)
    DECLF(a1z_i0, FB_IH1 + (w+8)*4 + 0)   DECLF(a1z_i1, FB_IH1 + (w+8)*4 + 1)
    DECLF(a1z_i2, FB_IH1 + (w+8)*4 + 2)   DECLF(a1z_i3, FB_IH1 + (w+8)*4 + 3)
    DECLF(a1z_h0, FB_HH1 + (w+8)*4 + 0)   DECLF(a1z_h1, FB_HH1 + (w+8)*4 + 1)
    DECLF(a1z_h2, FB_HH1 + (w+8)*4 + 2)   DECLF(a1z_h3, FB_HH1 + (w+8)*4 + 3)
    DECLF(a1n_i0, FB_IH1 + (16+w)*4 + 0)  DECLF(a1n_i1, FB_IH1 + (16+w)*4 + 1)
    DECLF(a1n_i2, FB_IH1 + (16+w)*4 + 2)  DECLF(a1n_i3, FB_IH1 + (16+w)*4 + 3)
    DECLF(a1n_h0, FB_HH1 + (16+w)*4 + 0)  DECLF(a1n_h1, FB_HH1 + (16+w)*4 + 1)
    DECLF(a1n_h2, FB_HH1 + (16+w)*4 + 2)  DECLF(a1n_h3, FB_HH1 + (16+w)*4 + 3)

    // ---- biases, f16x2-packed (16 regs). j0 = first hidden unit of this lane. ----
    const int j0 = 16 * w + 4 * (l >> 4);
    uint32_t B0r01 = pack2f(bih0[j0]+bhh0[j0],       bih0[j0+1]+bhh0[j0+1]);
    uint32_t B0r23 = pack2f(bih0[j0+2]+bhh0[j0+2],   bih0[j0+3]+bhh0[j0+3]);
    uint32_t B0z01 = pack2f(bih0[128+j0]+bhh0[128+j0],     bih0[129+j0]+bhh0[129+j0]);
    uint32_t B0z23 = pack2f(bih0[130+j0]+bhh0[130+j0],     bih0[131+j0]+bhh0[131+j0]);
    uint32_t B0x01 = pack2f(bih0[256+j0], bih0[257+j0]);
    uint32_t B0x23 = pack2f(bih0[258+j0], bih0[259+j0]);
    uint32_t B0h01 = pack2f(bhh0[256+j0], bhh0[257+j0]);
    uint32_t B0h23 = pack2f(bhh0[258+j0], bhh0[259+j0]);
    uint32_t B1r01 = pack2f(bih1[j0]+bhh1[j0],       bih1[j0+1]+bhh1[j0+1]);
    uint32_t B1r23 = pack2f(bih1[j0+2]+bhh1[j0+2],   bih1[j0+3]+bhh1[j0+3]);
    uint32_t B1z01 = pack2f(bih1[128+j0]+bhh1[128+j0],     bih1[129+j0]+bhh1[129+j0]);
    uint32_t B1z23 = pack2f(bih1[130+j0]+bhh1[130+j0],     bih1[131+j0]+bhh1[131+j0]);
    uint32_t B1x01 = pack2f(bih1[256+j0], bih1[257+j0]);
    uint32_t B1x23 = pack2f(bih1[258+j0], bih1[259+j0]);
    uint32_t B1h01 = pack2f(bhh1[256+j0], bhh1[257+j0]);
    uint32_t B1h23 = pack2f(bhh1[258+j0], bhh1[259+j0]);

    float h0o0 = 0.f, h0o1 = 0.f, h0o2 = 0.f, h0o3 = 0.f;   // h_old in regs
    float h1o0 = 0.f, h1o1 = 0.f, h1o2 = 0.f, h1o3 = 0.f;

    // zero h-frag buffers (both parities): 512+512 uint4, one of each per thread
    { uint4 z4 = {0u,0u,0u,0u};
      (&h0F[0][0][0])[lid] = z4;
      (&h1F[0][0][0])[lid] = z4; }

    // x stager: this thread owns (row = lid>>5, k2 = (lid&31)*2) of every x_t
    const int xrow = lid >> 5, xk = (lid & 31) * 2;
    const float* xbase = x + (size_t)(row0 + xrow) * TT * NIN + xk;
    const int xoff = ((xk >> 5) << 10) + (((((xk & 31) >> 3) * 16) + xrow) << 4) + ((xk & 7) << 1);
    float2 xr2;
    { float2 v0 = *(const float2*)xbase;                     // x_0
      *(uint32_t*)((char*)&xF[0][0][0] + xoff) = pack2f(v0.x, v0.y);
      xr2 = *(const float2*)(xbase + NIN); }                 // x_1

    // h-frag write offset for this lane (J = j0+ri, row = l&15)
    const int hoff = ((w >> 1) << 10)
                   + ((((2 * (w & 1) + ((l >> 4) >> 1)) * 16) + (l & 15)) << 4)
                   + (((l >> 4) & 1) << 3);

    __syncthreads();

    // Iter i: layer0 computes h0[i] (i<TT); layer1 computes h1[i-1] (i>=1).
    for (int i = 0; i <= TT; ++i) {
        const int p = i & 1;
        const uint4* bb0 = &h0F[p][0][0];                    // h0[i-1] frags
        uint4 bh00 = bb0[l], bh01 = bb0[64+l], bh02 = bb0[128+l], bh03 = bb0[192+l];

        if (i < TT) {                                        // ---- layer 0 ----
            const uint4* bxv = &xF[p][0][0];
            uint4 bx0 = bxv[l], bx1 = bxv[64 + l];
            f32x4 cr = {0,0,0,0}, cz = {0,0,0,0}, cx = {0,0,0,0}, ch = {0,0,0,0};
            MF(cr, a0r_i0, bx0)  MF(cr, a0r_i1, bx1)
            MF(cr, a0r_h0, bh00) MF(cr, a0r_h1, bh01) MF(cr, a0r_h2, bh02) MF(cr, a0r_h3, bh03)
            MF(cz, a0z_i0, bx0)  MF(cz, a0z_i1, bx1)
            MF(cz, a0z_h0, bh00) MF(cz, a0z_h1, bh01) MF(cz, a0z_h2, bh02) MF(cz, a0z_h3, bh03)
            MF(cx, a0n_i0, bx0)  MF(cx, a0n_i1, bx1)
            MF(ch, a0n_h0, bh00) MF(ch, a0n_h1, bh01) MF(ch, a0n_h2, bh02) MF(ch, a0n_h3, bh03)
            float vr0,vr1,vr2,vr3, vz0,vz1,vz2,vz3, vx0,vx1,vx2,vx3, vh0,vh1,vh2,vh3;
            UNPK2(vr0,vr1,B0r01) UNPK2(vr2,vr3,B0r23)
            UNPK2(vz0,vz1,B0z01) UNPK2(vz2,vz3,B0z23)
            UNPK2(vx0,vx1,B0x01) UNPK2(vx2,vx3,B0x23)
            UNPK2(vh0,vh1,B0h01) UNPK2(vh2,vh3,B0h23)
            float nh0, nh1, nh2, nh3;
            CMB(0, cr,cz,cx,ch, vr0,vz0,vx0,vh0, h0o0, nh0)
            CMB(1, cr,cz,cx,ch, vr1,vz1,vx1,vh1, h0o1, nh1)
            CMB(2, cr,cz,cx,ch, vr2,vz2,vx2,vh2, h0o2, nh2)
            CMB(3, cr,cz,cx,ch, vr3,vz3,vx3,vh3, h0o3, nh3)
            uint2 hw; hw.x = pack2f(nh0, nh1); hw.y = pack2f(nh2, nh3);
            *(uint2*)((char*)&h0F[1 - p][0][0] + hoff) = hw;
        }

        if (i >= 1) {                                        // ---- layer 1 ----
            const uint4* bb1 = &h1F[p][0][0];                // h1[i-2] frags
            uint4 bh10 = bb1[l], bh11 = bb1[64+l], bh12 = bb1[128+l], bh13 = bb1[192+l];
            f32x4 cr = {0,0,0,0}, cz = {0,0,0,0}, cx = {0,0,0,0}, ch = {0,0,0,0};
            MF(cr, a1r_i0, bh00) MF(cr, a1r_i1, bh01) MF(cr, a1r_i2, bh02) MF(cr, a1r_i3, bh03)
            MF(cr, a1r_h0, bh10) MF(cr, a1r_h1, bh11) MF(cr, a1r_h2, bh12) MF(cr, a1r_h3, bh13)
            MF(cz, a1z_i0, bh00) MF(cz, a1z_i1, bh01) MF(cz, a1z_i2, bh02) MF(cz, a1z_i3, bh03)
            MF(cz, a1z_h0, bh10) MF(cz, a1z_h1, bh11) MF(cz, a1z_h2, bh12) MF(cz, a1z_h3, bh13)
            MF(cx, a1n_i0, bh00) MF(cx, a1n_i1, bh01) MF(cx, a1n_i2, bh02) MF(cx, a1n_i3, bh03)
            MF(ch, a1n_h0, bh10) MF(ch, a1n_h1, bh11) MF(ch, a1n_h2, bh12) MF(ch, a1n_h3, bh13)
            float vr0,vr1,vr2,vr3, vz0,vz1,vz2,vz3, vx0,vx1,vx2,vx3, vh0,vh1,vh2,vh3;
            UNPK2(vr0,vr1,B1r01) UNPK2(vr2,vr3,B1r23)
            UNPK2(vz0,vz1,B1z01) UNPK2(vz2,vz3,B1z23)
            UNPK2(vx0,vx1,B1x01) UNPK2(vx2,vx3,B1x23)
            UNPK2(vh0,vh1,B1h01) UNPK2(vh2,vh3,B1h23)
            float nh0, nh1, nh2, nh3;
            CMB(0, cr,cz,cx,ch, vr0,vz0,vx0,vh0, h1o0, nh0)
            CMB(1, cr,cz,cx,ch, vr1,vz1,vx1,vh1, h1o1, nh1)
            CMB(2, cr,cz,cx,ch, vr2,vz2,vx2,vh2, h1o2, nh2)
            CMB(3, cr,cz,cx,ch, vr3,vz3,vx3,vh3, h1o3, nh3)
            uint2 hw; hw.x = pack2f(nh0, nh1); hw.y = pack2f(nh2, nh3);
            *(uint2*)((char*)&h1F[1 - p][0][0] + hoff) = hw;
        }

        // x staging into the buffer next iter reads
        if (i + 1 < TT)
            *(uint32_t*)((char*)&xF[1 - p][0][0] + xoff) = pack2f(xr2.x, xr2.y);
        if (i + 2 < TT)
            xr2 = *(const float2*)(xbase + (size_t)(i + 2) * NIN);

        BARS();   // LDS-only drain; global prefetch stays in flight (T4)
    }

    // ---------------- FC head ----------------
    { f32x4 hv; hv[0] = h1o0; hv[1] = h1o1; hv[2] = h1o2; hv[3] = h1o3;
      *(f32x4*)&h1f[l & 15][16 * w + 4 * (l >> 4)] = hv; }
    __syncthreads();

    { const int fcj = lid & 127, rb = lid >> 7;              // 4 rows per thread
      float a0 = fc1b[fcj], a1 = a0, a2 = a0, a3 = a0;
      const float* fw = fc1w + fcj * HH;
      #pragma unroll 4
      for (int k = 0; k < HH; ++k) {
          float wv = fw[k];
          a0 = fmaf(wv, h1f[rb][k], a0);
          a1 = fmaf(wv, h1f[rb + 4][k], a1);
          a2 = fmaf(wv, h1f[rb + 8][k], a2);
          a3 = fmaf(wv, h1f[rb + 12][k], a3);
      }
      float s2 = fc2w[fcj];
      pFC[rb][fcj]      = fmaxf(a0, 0.f) * s2;
      pFC[rb + 4][fcj]  = fmaxf(a1, 0.f) * s2;
      pFC[rb + 8][fcj]  = fmaxf(a2, 0.f) * s2;
      pFC[rb + 12][fcj] = fmaxf(a3, 0.f) * s2; }
    __syncthreads();
    if (lid < 128) {
        const int r = lid >> 3, seg = lid & 7;
        float s = 0.f;
        #pragma unroll
        for (int m2 = 0; m2 < 16; ++m2) s += pFC[r][seg * 16 + m2];
        p2[r][seg] = s;
    }
    __syncthreads();
    if (lid < RPB) {
        float s = fc2b[0];
        #pragma unroll
        for (int q = 0; q < 8; ++q) s += p2[lid][q];
        out[row0 + lid] = s;
    }
}

extern "C" void kernel_launch(void* const* d_in, const int* in_sizes, int n_in,
                              void* d_out, int out_size, void* d_ws, size_t ws_size,
                              hipStream_t stream) {
    const float* x    = (const float*)d_in[0];
    const float* Wih0 = (const float*)d_in[1];
    const float* Whh0 = (const float*)d_in[2];
    const float* bih0 = (const float*)d_in[3];
    const float* bhh0 = (const float*)d_in[4];
    const float* Wih1 = (const float*)d_in[5];
    const float* Whh1 = (const float*)d_in[6];
    const float* bih1 = (const float*)d_in[7];
    const float* bhh1 = (const float*)d_in[8];
    const float* fc1w = (const float*)d_in[9];
    const float* fc1b = (const float*)d_in[10];
    const float* fc2w = (const float*)d_in[11];
    const float* fc2b = (const float*)d_in[12];

    uint4* ws = (uint4*)d_ws;   // 336 KB of f16 A-fragments

    pack_frags<<<dim3(84), dim3(256), 0, stream>>>(Wih0, Whh0, Wih1, Whh1, ws);
    gru_mfma<<<dim3(NWG), dim3(NTHR), 0, stream>>>(
        x, ws, bih0, bhh0, bih1, bhh1, fc1w, fc1b, fc2w, fc2b, (float*)d_out);
}